// Round 9
// baseline (293.683 us; speedup 1.0000x reference)
//
#include <hip/hip_runtime.h>
#include <hip/hip_bf16.h>
#include <math.h>

// Head: B=8, T=4096, E=1024, H=64. out = softmax_causal(QK^T/8) V, fp32 out.
// R14 = R13 + staggered K-chunk order in proj. Evidence: three structurally
// different proj schedules (R2/R9/R13) all plateau at 73-101us, ~1 TB/s,
// all pipes idle, conflicts 0 (R13) -> limit is the ADDRESS STREAM, not the
// schedule. A-gathers touch 16 rows of x at stride 4096B and all 512 blocks
// walk chunks 0..31 in lockstep -> HBM channel camping (period divides 4KB).
// Fix: block bid starts at chunk c0 = bid&31 and wraps (cc=(c0+c)&31);
// K-accumulation is order-independent; vmcnt ledger unchanged. At any
// instant blocks cover all 32 k-offsets -> traffic spreads across the full
// interleave period. attn/comb/wt unchanged (R9 verbatim).
// Fixed-reference softmax p=2^s (q pre-scaled 0.125*log2e) throughout.

#define BB 8
#define TT 4096
#define EE 1024
#define HH 64
#define NSLOT 160   // split-chunks per batch: sum_{jq<64} (jq/16+1)
#define SLOTF 4160  // floats per partial slot: 64*64 o + 64 l

typedef __attribute__((ext_vector_type(8))) short short8;
typedef __attribute__((ext_vector_type(4))) float floatx4;
typedef short8 __attribute__((may_alias)) short8_a;
typedef uint2 __attribute__((may_alias)) uint2_a;
typedef uint4 __attribute__((may_alias)) uint4_a;
typedef float4 __attribute__((may_alias)) float4_a;

#define GLDS(gp, lp)                                                     \
  __builtin_amdgcn_global_load_lds(                                      \
      (const __attribute__((address_space(1))) unsigned int*)(gp),       \
      (__attribute__((address_space(3))) unsigned int*)(lp), 16, 0, 0)

__device__ __forceinline__ unsigned short f2bf(float f) {
  union { float f; unsigned int u; } v; v.f = f;
  unsigned int r = v.u + 0x7fffu + ((v.u >> 16) & 1u);  // RNE
  return (unsigned short)(r >> 16);
}
__device__ __forceinline__ unsigned int pk2(float a, float b) {
  unsigned int r;
  asm("v_cvt_pk_bf16_f32 %0, %1, %2" : "=v"(r) : "v"(a), "v"(b));
  return r;
}
__device__ __forceinline__ floatx4 fzero() {
  floatx4 z = {0.f, 0.f, 0.f, 0.f};
  return z;
}
__device__ __forceinline__ floatx4 mfma_bf16(short8 a, short8 b, floatx4 c) {
  return __builtin_amdgcn_mfma_f32_16x16x32_bf16(a, b, c, 0, 0, 0);
}
__device__ __forceinline__ short8 pack8(float4 a, float4 b) {
  union { unsigned int u[4]; short8 s; } r;
  r.u[0] = pk2(a.x, a.y);
  r.u[1] = pk2(a.z, a.w);
  r.u[2] = pk2(b.x, b.y);
  r.u[3] = pk2(b.z, b.w);
  return r.s;
}

// ---------------------------------------------------------------------------
// Kernel 1: W[e][h] fp32 -> wt3[m][h][e] bf16 (m=0:K,1:Q,2:V). 48 blocks.
// ---------------------------------------------------------------------------
__global__ __launch_bounds__(256) void wt_kernel(
    const float* __restrict__ Wk, const float* __restrict__ Wq,
    const float* __restrict__ Wv, unsigned short* __restrict__ wt3) {
  __shared__ float tile[64][65];
  const int m = blockIdx.y;
  const int eb = blockIdx.x;  // e-block of 64
  const float* W = (m == 0) ? Wk : ((m == 1) ? Wq : Wv);
  const int t = threadIdx.x;
  {
    const int r = t >> 2;            // e-local
    const int c0 = (t & 3) * 16;     // h
    const float* src = W + (size_t)(eb * 64 + r) * 64 + c0;
#pragma unroll
    for (int i = 0; i < 16; ++i) tile[r][c0 + i] = src[i];
  }
  __syncthreads();
  {
    const int h = t >> 2;
    const int e0 = (t & 3) * 16;
    unsigned int w[8];
#pragma unroll
    for (int i = 0; i < 8; ++i)
      w[i] = pk2(tile[e0 + 2 * i][h], tile[e0 + 2 * i + 1][h]);
    unsigned short* dst = wt3 + (size_t)(m * 64 + h) * EE + eb * 64 + e0;
    ((uint4_a*)dst)[0] = make_uint4(w[0], w[1], w[2], w[3]);
    ((uint4_a*)(dst + 8))[0] = make_uint4(w[4], w[5], w[6], w[7]);
  }
}

// ---------------------------------------------------------------------------
// Kernel 2: projections. 512 blocks x 256 thr; block = 64 rows x 192 cols.
// K-chunk 32, STAGGERED: block walks chunks cc=(c0+c)&31, c0=bid&31, so the
// in-flight k-offsets are uniformly spread across the 4KB x-row period
// (anti channel-camping). B (weights): 3-deep GLDS-staged LDS frags
// (12 x 1KB/chunk, 3 GLDS/wave). A (x rows): lane-private float4 global
// loads to regs (no LDS). Steady state per chunk: issue A(c+1), B(c+2);
// compute c; s_waitcnt vmcnt(3) (B(c+2) in flight); s_barrier.
// Q pre-scaled by 0.125*log2(e) so attn uses exp2.
// ---------------------------------------------------------------------------
__global__ __launch_bounds__(256) void proj_kernel(
    const float* __restrict__ x, const unsigned short* __restrict__ wt3,
    unsigned short* __restrict__ kws, unsigned short* __restrict__ qws,
    unsigned short* __restrict__ vtws) {
  __shared__ __align__(16) unsigned char LB[3][12288];  // B frags only
  const int t = threadIdx.x;
  const int wv = t >> 6, lane = t & 63;
  const int l16 = lane & 15, quad = lane >> 4;
  const int mshalf = wv & 1;        // row half (32 rows)
  const int jbase = (wv >> 1) * 6;  // col-tile group (6 of 12)
  const size_t row0 = (size_t)blockIdx.x * 64;
  const int c0 = (int)blockIdx.x & 31;  // staggered K start

  floatx4 acc[6][2];
#pragma unroll
  for (int j = 0; j < 6; ++j)
#pragma unroll
    for (int m2 = 0; m2 < 2; ++m2) acc[j][m2] = fzero();

  // A: lane-private fragment source. row = row0 + mshalf*32 + m2*16 + l16,
  // k = cc*32 + quad*8 + h*4 .. +3 (float4).
  const float* xbase = x + (row0 + mshalf * 32 + l16) * EE + quad * 8;

  // B: 12 GLDS per block-chunk = 3 per wave (idx = wv*3+i, frag idx*1KB).
#define STAGE_B(bufp, cc)                                                      \
  {                                                                            \
    _Pragma("unroll") for (int i = 0; i < 3; ++i) {                            \
      const int idx = wv * 3 + i;                                              \
      const unsigned short* gp =                                               \
          wt3 + (size_t)(idx * 16 + l16) * EE + (cc) * 32 + quad * 8;          \
      GLDS(gp, (bufp) + idx * 1024);                                           \
    }                                                                          \
  }

  float4 ra[2][2], rb[2][2];  // [m2][h]
#pragma unroll
  for (int m2 = 0; m2 < 2; ++m2)
#pragma unroll
    for (int h = 0; h < 2; ++h)
      ra[m2][h] = *(const float4_a*)(xbase + (size_t)m2 * 16 * EE + c0 * 32 + h * 4);

  STAGE_B(&LB[0][0], c0);
  STAGE_B(&LB[1][0], (c0 + 1) & 31);
  // outstanding: A(0)=4 (oldest), B(0)=3, B(1)=3 -> vmcnt(3) completes
  // A(0)+B(0), keeps B(1) in flight.
  asm volatile("s_waitcnt vmcnt(3)" ::: "memory");
  __builtin_amdgcn_s_barrier();
  __builtin_amdgcn_sched_barrier(0);

  int cur = 0;
  for (int c = 0; c < 32; ++c) {
    // issue next A into regs, next-next B into the freed buffer
    if (c + 1 < 32) {
      const int cc1 = (c0 + c + 1) & 31;
#pragma unroll
      for (int m2 = 0; m2 < 2; ++m2)
#pragma unroll
        for (int h = 0; h < 2; ++h)
          rb[m2][h] = *(const float4_a*)(xbase + (size_t)m2 * 16 * EE +
                                         cc1 * 32 + h * 4);
    }
    if (c + 2 < 32) {
      int sb = cur + 2;
      if (sb >= 3) sb -= 3;
      STAGE_B(&LB[sb][0], (c0 + c + 2) & 31);
    }
    // compute chunk (c0+c)&31
    short8 af[2];
#pragma unroll
    for (int m2 = 0; m2 < 2; ++m2) af[m2] = pack8(ra[m2][0], ra[m2][1]);
    const unsigned char* Bb = &LB[cur][0];
#pragma unroll
    for (int jj = 0; jj < 6; ++jj) {
      short8 bfv = *(const short8_a*)(Bb + (size_t)(jbase + jj) * 1024 +
                                      lane * 16);
#pragma unroll
      for (int m2 = 0; m2 < 2; ++m2)
        acc[jj][m2] = mfma_bf16(af[m2], bfv, acc[jj][m2]);
    }
    if (c < 31) {
      if (c + 2 < 32) {
        // outstanding: B(c+1)=3 (oldest), A(c+1)=4, B(c+2)=3 (newest).
        // vmcnt(3) completes B(c+1)+A(c+1); B(c+2) stays in flight.
        asm volatile("s_waitcnt vmcnt(3)" ::: "memory");
      } else {
        asm volatile("s_waitcnt vmcnt(0)" ::: "memory");
      }
      __builtin_amdgcn_s_barrier();
      __builtin_amdgcn_sched_barrier(0);
#pragma unroll
      for (int m2 = 0; m2 < 2; ++m2)
#pragma unroll
        for (int h = 0; h < 2; ++h) ra[m2][h] = rb[m2][h];
    }
    cur = (cur == 2) ? 0 : cur + 1;
  }
#undef STAGE_B

  const int b = (int)(row0 >> 12);
  const int tt0 = (int)(row0 & (TT - 1));
#pragma unroll
  for (int j = 0; j < 6; ++j) {
    const int jg = jbase + j;
    const int m = jg >> 2;
    const int h0 = (jg & 3) * 16;
#pragma unroll
    for (int m2 = 0; m2 < 2; ++m2) {
      floatx4 a = acc[j][m2];
      const int rbase = mshalf * 32 + m2 * 16 + quad * 4;
      if (m == 0) {
#pragma unroll
        for (int r = 0; r < 4; ++r)
          kws[(row0 + rbase + r) * HH + h0 + l16] = f2bf(a[r]);
      } else if (m == 1) {
        // 0.125 (1/sqrt(H)) * log2(e): attn does p = 2^s
#pragma unroll
        for (int r = 0; r < 4; ++r)
          qws[(row0 + rbase + r) * HH + h0 + l16] = f2bf(a[r] * 0.18033688011112042f);
      } else {  // v transposed [B,64,T]
        uint2 p;
        p.x = pk2(a[0], a[1]);
        p.y = pk2(a[2], a[3]);
        ((uint2_a*)&vtws[(size_t)(b * 64 + h0 + l16) * TT + tt0 + rbase])[0] = p;
      }
    }
  }
}

// ---------------------------------------------------------------------------
// Kernel 3: flash attention. Templated:
//  SPLIT=1: block=(b,jq,split); cid in [0,160) enumerates (jq,s), S(jq)=
//    jq/16+1 splits of key-tile range [0,jq]; 8..17 iters/block, 1280 blocks.
//    Writes partial fp32 (o,l) to slot blockIdx.x; comb_kernel finishes.
//  SPLIT=0 (ws fallback, == verified R5): 512 blocks, paired jq mapping,
//    full key range, in-kernel normalize, direct out write.
// Fixed-reference softmax: p = 2^s (q pre-scaled by 0.125*log2e), masked
// lanes 2^(-1e30) = 0. id = b + 8*cid keeps batch b on XCD b (L2 locality).
// ---------------------------------------------------------------------------
template <bool SPLIT>
__global__ __launch_bounds__(256) void attn_kernel(
    const unsigned short* __restrict__ kws, const unsigned short* __restrict__ qws,
    const unsigned short* __restrict__ vtws, float* __restrict__ dst) {
  __shared__ unsigned short KV[2][16][512];  // 32 KB dbuf
  __shared__ unsigned short pb[4][16][72];   // per-wave P, +8 pad
  const int t = threadIdx.x;
  const int wv = t >> 6, lane = t & 63;
  const int l16 = lane & 15, quad = lane >> 4;
  const int id = (int)blockIdx.x;
  int b, jq, kt0, kt1;
  if (SPLIT) {
    b = id & 7;
    const int cid = id >> 3;  // 0..159
    int s, S;
    if (cid < 16) {
      jq = cid; s = 0; S = 1;
    } else if (cid < 48) {
      const int u = cid - 16; jq = 16 + (u >> 1); s = u & 1; S = 2;
    } else if (cid < 96) {
      const int u = cid - 48; const int d = u / 3; jq = 32 + d; s = u - 3 * d; S = 3;
    } else {
      const int u = cid - 96; jq = 48 + (u >> 2); s = u & 3; S = 4;
    }
    const int n = jq + 1;
    kt0 = (s * n) / S;
    kt1 = ((s + 1) * n) / S;
  } else {
    const int r255 = id & 255;
    b = r255 & 7;
    const int m = r255 >> 3;  // 0..31
    jq = (id < 256) ? m : 63 - m;
    kt0 = 0;
    kt1 = jq + 1;
  }
  const int q0 = jq * 64;
  const int qrow = q0 + wv * 16 + l16;

  const unsigned short* qp = qws + ((size_t)b * TT + qrow) * HH + quad * 8;
  short8 qa0 = *(const short8_a*)(qp);
  short8 qa1 = *(const short8_a*)(qp + 32);

  floatx4 o[4];
#pragma unroll
  for (int nt = 0; nt < 4; ++nt) o[nt] = fzero();
  float lsum = 0.f;

#define STAGE_KV(buf, ks)                                                      \
  {                                                                            \
    _Pragma("unroll") for (int i = 0; i < 4; ++i) {                            \
      const int idx = wv * 4 + i;                                              \
      const unsigned short* gp;                                                \
      if (idx < 8) {                                                           \
        const int nt = idx >> 1, f = idx & 1;                                  \
        gp = kws + ((size_t)b * TT + (ks) + nt * 16 + l16) * HH + f * 32 +     \
             quad * 8;                                                         \
      } else {                                                                 \
        const int nt = (idx - 8) >> 1, f = idx & 1;                            \
        gp = vtws + ((size_t)(b * 64 + nt * 16 + l16)) * TT + (ks) + f * 32 +  \
             quad * 8;                                                         \
      }                                                                        \
      GLDS(gp, &KV[buf][idx][0]);                                              \
    }                                                                          \
  }

  STAGE_KV(0, kt0 * 64);
  __syncthreads();

  for (int kt = kt0; kt < kt1; ++kt) {
    const int cur = (kt - kt0) & 1;
    const int ks = kt * 64;
    if (kt + 1 < kt1) STAGE_KV(cur ^ 1, ks + 64);

    floatx4 sc[4];
#pragma unroll
    for (int nt = 0; nt < 4; ++nt) {
      short8 kf0 = *(const short8_a*)&KV[cur][nt * 2][lane * 8];
      short8 kf1 = *(const short8_a*)&KV[cur][nt * 2 + 1][lane * 8];
      floatx4 z = fzero();
      z = mfma_bf16(kf0, qa0, z);
      z = mfma_bf16(kf1, qa1, z);
      sc[nt] = z;
    }
    if (kt == jq) {  // causal mask on diagonal tile -> exp2 gives exact 0
#pragma unroll
      for (int nt = 0; nt < 4; ++nt)
#pragma unroll
        for (int r = 0; r < 4; ++r) {
          const int key = ks + nt * 16 + quad * 4 + r;
          if (key > qrow) sc[nt][r] = -1e30f;
        }
    }
    // fixed-reference softmax: p = 2^s (s already in log2 domain)
#pragma unroll
    for (int nt = 0; nt < 4; ++nt) {
      const float p0 = exp2f(sc[nt][0]);
      const float p1 = exp2f(sc[nt][1]);
      const float p2 = exp2f(sc[nt][2]);
      const float p3 = exp2f(sc[nt][3]);
      lsum += (p0 + p1) + (p2 + p3);
      uint2 pw;
      pw.x = pk2(p0, p1);
      pw.y = pk2(p2, p3);
      ((uint2_a*)&pb[wv][l16][nt * 16 + quad * 4])[0] = pw;
    }
    // P frags (same-wave LDS RAW; lgkmcnt handles)
    short8 pf0 = *(const short8_a*)&pb[wv][l16][quad * 8];
    short8 pf1 = *(const short8_a*)&pb[wv][l16][quad * 8 + 32];
#pragma unroll
    for (int nt = 0; nt < 4; ++nt) {
      short8 vf0 = *(const short8_a*)&KV[cur][8 + nt * 2][lane * 8];
      short8 vf1 = *(const short8_a*)&KV[cur][8 + nt * 2 + 1][lane * 8];
      o[nt] = mfma_bf16(vf0, pf0, o[nt]);
      o[nt] = mfma_bf16(vf1, pf1, o[nt]);
    }
    __syncthreads();
  }
#undef STAGE_KV

  // l over the 4 quads of this query column
  float lr = lsum;
  lr += __shfl_xor(lr, 16);
  lr += __shfl_xor(lr, 32);

  if (SPLIT) {
    float* op = dst + (size_t)id * SLOTF;
    const int ql = wv * 16 + l16;
#pragma unroll
    for (int nt = 0; nt < 4; ++nt) {
      float4 st;
      st.x = o[nt][0];
      st.y = o[nt][1];
      st.z = o[nt][2];
      st.w = o[nt][3];
      *(float4_a*)&op[(size_t)ql * 64 + nt * 16 + quad * 4] = st;
    }
    if (lane < 16) op[4096 + wv * 16 + lane] = lr;
  } else {
    const float inv = 1.0f / lr;
#pragma unroll
    for (int nt = 0; nt < 4; ++nt) {
      float4 st;
      st.x = o[nt][0] * inv;
      st.y = o[nt][1] * inv;
      st.z = o[nt][2] * inv;
      st.w = o[nt][3] * inv;
      *(float4_a*)&dst[((size_t)b * TT + qrow) * HH + nt * 16 + quad * 4] = st;
    }
  }
}

// ---------------------------------------------------------------------------
// Kernel 4 (split path): combine partials. 512 blocks = (b, jq); sums S(jq)
// slots of (o, l), writes out = o_sum / l_sum. Slots written by same-b attn
// blocks live on the same XCD (id = b mod 8) -> mostly L2 reads.
// ---------------------------------------------------------------------------
__global__ __launch_bounds__(256) void comb_kernel(
    const float* __restrict__ part, float* __restrict__ out) {
  const int id = (int)blockIdx.x;
  const int b = id & 7;
  const int jq = id >> 3;  // 0..63
  const int tq = jq >> 4;
  const int S = tq + 1;
  const int P = 8 * tq * (tq + 1) + (jq & 15) * S;  // prefix of (jq,0) in cid space
  const int t = threadIdx.x;
  const int r0 = t >> 6;   // 0..3
  const int h = t & 63;
  const float* s0 = part + (size_t)(b + 8 * P) * SLOTF;
  const size_t sstr = (size_t)8 * SLOTF;  // slot stride between consecutive s

#pragma unroll 4
  for (int i = 0; i < 16; ++i) {
    const int r = i * 4 + r0;
    float acc = 0.f, l = 0.f;
    for (int s2 = 0; s2 < S; ++s2) {
      acc += s0[(size_t)s2 * sstr + (size_t)r * 64 + h];
      l += s0[(size_t)s2 * sstr + 4096 + r];
    }
    out[((size_t)b * TT + jq * 64 + r) * HH + h] = acc / l;
  }
}

// ---------------------------------------------------------------------------
extern "C" void kernel_launch(void* const* d_in, const int* in_sizes, int n_in,
                              void* d_out, int out_size, void* d_ws, size_t ws_size,
                              hipStream_t stream) {
  const float* x = (const float*)d_in[0];
  const float* Wk = (const float*)d_in[1];
  const float* Wq = (const float*)d_in[2];
  const float* Wv = (const float*)d_in[3];
  float* out = (float*)d_out;

  // ws layout: k bf16 [B,T,64] | q bf16 [B,T,64] | vT bf16 [B,64,T] |
  //            wt3 bf16 [3,64,1024] | partials fp32 [1280][4160] (if room)
  unsigned short* kws = (unsigned short*)d_ws;
  unsigned short* qws = kws + (size_t)BB * TT * HH;
  unsigned short* vtws = qws + (size_t)BB * TT * HH;
  unsigned short* wt3 = vtws + (size_t)BB * TT * HH;
  float* part = (float*)(wt3 + (size_t)3 * HH * EE);

  const size_t base_bytes = (size_t)3 * BB * TT * HH * 2 + (size_t)3 * HH * EE * 2;
  const size_t need = base_bytes + (size_t)BB * NSLOT * SLOTF * 4;
  const bool use_split = (ws_size >= need);

  hipLaunchKernelGGL(wt_kernel, dim3(16, 3), dim3(256), 0, stream, Wk, Wq, Wv, wt3);
  hipLaunchKernelGGL(proj_kernel, dim3(512), dim3(256), 0, stream, x, wt3, kws, qws,
                     vtws);
  if (use_split) {
    hipLaunchKernelGGL((attn_kernel<true>), dim3(BB * NSLOT), dim3(256), 0, stream,
                       kws, qws, vtws, part);
    hipLaunchKernelGGL(comb_kernel, dim3(512), dim3(256), 0, stream, part, out);
  } else {
    hipLaunchKernelGGL((attn_kernel<false>), dim3(512), dim3(256), 0, stream,
                       kws, qws, vtws, out);
  }
}

// Round 11
// 290.387 us; speedup vs baseline: 1.0113x; 1.0113x over previous
//
#include <hip/hip_runtime.h>
#include <hip/hip_bf16.h>
#include <math.h>

// Head: B=8, T=4096, E=1024, H=64. out = softmax_causal(QK^T/8) V, fp32 out.
// R16 == R15 resubmit (R15 hit "container failed twice" -- same infra
// signature as R1/R8, both of which passed verbatim on resubmit; full audit
// found no hang/OOB/spill in the burst-A proj: vmcnt ledger closed,
// barriers wave-uniform, <=210 VGPR).
// R15 = R13 + A-loads grouped 4 chunks at a time (512 B contiguous per
// x-row per burst). Evidence: R2/R9/R13/R14 proj all pin at ~80us, ~1 TB/s,
// pipes idle, conflicts 0 -> invariant is 128 B per row-visit across 32K
// concurrent 4KB-strided row streams = DRAM page thrash (every access opens
// a page). Burst-issue 512 B/row so same-page requests coalesce in the DRAM
// queue (~4 line hits per page open). A regs ping-pong GA/GB (static
// indexing), B keeps R13's 3-deep GLDS pipeline. vmcnt ledger: group-sub0
// ends vmcnt(19) (A16+B3 newest), other subs vmcnt(3), tail vmcnt(0).
// attn split-K + comb + wt unchanged (best-measured config).
// Fixed-reference softmax p=2^s (q pre-scaled 0.125*log2e) throughout.

#define BB 8
#define TT 4096
#define EE 1024
#define HH 64
#define NSLOT 160   // split-chunks per batch: sum_{jq<64} (jq/16+1)
#define SLOTF 4160  // floats per partial slot: 64*64 o + 64 l

typedef __attribute__((ext_vector_type(8))) short short8;
typedef __attribute__((ext_vector_type(4))) float floatx4;
typedef short8 __attribute__((may_alias)) short8_a;
typedef uint2 __attribute__((may_alias)) uint2_a;
typedef uint4 __attribute__((may_alias)) uint4_a;
typedef float4 __attribute__((may_alias)) float4_a;

#define GLDS(gp, lp)                                                     \
  __builtin_amdgcn_global_load_lds(                                      \
      (const __attribute__((address_space(1))) unsigned int*)(gp),       \
      (__attribute__((address_space(3))) unsigned int*)(lp), 16, 0, 0)

__device__ __forceinline__ unsigned short f2bf(float f) {
  union { float f; unsigned int u; } v; v.f = f;
  unsigned int r = v.u + 0x7fffu + ((v.u >> 16) & 1u);  // RNE
  return (unsigned short)(r >> 16);
}
__device__ __forceinline__ unsigned int pk2(float a, float b) {
  unsigned int r;
  asm("v_cvt_pk_bf16_f32 %0, %1, %2" : "=v"(r) : "v"(a), "v"(b));
  return r;
}
__device__ __forceinline__ floatx4 fzero() {
  floatx4 z = {0.f, 0.f, 0.f, 0.f};
  return z;
}
__device__ __forceinline__ floatx4 mfma_bf16(short8 a, short8 b, floatx4 c) {
  return __builtin_amdgcn_mfma_f32_16x16x32_bf16(a, b, c, 0, 0, 0);
}
__device__ __forceinline__ short8 pack8(float4 a, float4 b) {
  union { unsigned int u[4]; short8 s; } r;
  r.u[0] = pk2(a.x, a.y);
  r.u[1] = pk2(a.z, a.w);
  r.u[2] = pk2(b.x, b.y);
  r.u[3] = pk2(b.z, b.w);
  return r.s;
}

// ---------------------------------------------------------------------------
// Kernel 1: W[e][h] fp32 -> wt3[m][h][e] bf16 (m=0:K,1:Q,2:V). 48 blocks.
// ---------------------------------------------------------------------------
__global__ __launch_bounds__(256) void wt_kernel(
    const float* __restrict__ Wk, const float* __restrict__ Wq,
    const float* __restrict__ Wv, unsigned short* __restrict__ wt3) {
  __shared__ float tile[64][65];
  const int m = blockIdx.y;
  const int eb = blockIdx.x;  // e-block of 64
  const float* W = (m == 0) ? Wk : ((m == 1) ? Wq : Wv);
  const int t = threadIdx.x;
  {
    const int r = t >> 2;            // e-local
    const int c0 = (t & 3) * 16;     // h
    const float* src = W + (size_t)(eb * 64 + r) * 64 + c0;
#pragma unroll
    for (int i = 0; i < 16; ++i) tile[r][c0 + i] = src[i];
  }
  __syncthreads();
  {
    const int h = t >> 2;
    const int e0 = (t & 3) * 16;
    unsigned int w[8];
#pragma unroll
    for (int i = 0; i < 8; ++i)
      w[i] = pk2(tile[e0 + 2 * i][h], tile[e0 + 2 * i + 1][h]);
    unsigned short* dst = wt3 + (size_t)(m * 64 + h) * EE + eb * 64 + e0;
    ((uint4_a*)dst)[0] = make_uint4(w[0], w[1], w[2], w[3]);
    ((uint4_a*)(dst + 8))[0] = make_uint4(w[4], w[5], w[6], w[7]);
  }
}

// ---------------------------------------------------------------------------
// Kernel 2: projections. 512 blocks x 256 thr; block = 64 rows x 192 cols.
// A (x rows): lane-private float4 loads, GROUPED: at group g (4 K32-chunks)
// issue all 16 loads covering floats [g*128,(g+1)*128) of the lane's two
// rows -> 512 B contiguous per row enters the DRAM queue as one burst.
// GA/GB register ping-pong, statically indexed (unrolled subs). B (weights,
// L2-resident): R13's 3-deep GLDS-staged LDS frags (12 x 1KB, 3/wave).
// Waits per sub-chunk: sub0 vmcnt(19) [A16+B3 newest], subs 1-3 vmcnt(3),
// tail vmcnt(0); s_barrier + sched_barrier after each.
// Q pre-scaled by 0.125*log2(e) so attn uses exp2.
// ---------------------------------------------------------------------------
__global__ __launch_bounds__(256) void proj_kernel(
    const float* __restrict__ x, const unsigned short* __restrict__ wt3,
    unsigned short* __restrict__ kws, unsigned short* __restrict__ qws,
    unsigned short* __restrict__ vtws) {
  __shared__ __align__(16) unsigned char LB[3][12288];  // B frags only
  const int t = threadIdx.x;
  const int wv = t >> 6, lane = t & 63;
  const int l16 = lane & 15, quad = lane >> 4;
  const int mshalf = wv & 1;        // row half (32 rows)
  const int jbase = (wv >> 1) * 6;  // col-tile group (6 of 12)
  const size_t row0 = (size_t)blockIdx.x * 64;

  floatx4 acc[6][2];
#pragma unroll
  for (int j = 0; j < 6; ++j)
#pragma unroll
    for (int m2 = 0; m2 < 2; ++m2) acc[j][m2] = fzero();

  // A: lane-private fragment source. row = row0 + mshalf*32 + m2*16 + l16,
  // group g covers floats g*128 + s*32 + quad*8 + h*4 (s=0..3, h=0..1).
  const float* xbase = x + (row0 + mshalf * 32 + l16) * EE + quad * 8;

  // B: 12 GLDS per block-chunk = 3 per wave (idx = wv*3+i, frag idx*1KB).
#define STAGE_B(bufp, cc)                                                      \
  {                                                                            \
    _Pragma("unroll") for (int i = 0; i < 3; ++i) {                            \
      const int idx = wv * 3 + i;                                              \
      const unsigned short* gp =                                               \
          wt3 + (size_t)(idx * 16 + l16) * EE + (cc) * 32 + quad * 8;          \
      GLDS(gp, (bufp) + idx * 1024);                                           \
    }                                                                          \
  }

  float4 GA[4][2][2], GB[4][2][2];  // [sub][m2][h]

#define LOAD_GROUP(DST, g)                                                     \
  {                                                                            \
    _Pragma("unroll") for (int s = 0; s < 4; ++s)                              \
    _Pragma("unroll") for (int m2 = 0; m2 < 2; ++m2)                           \
    _Pragma("unroll") for (int h = 0; h < 2; ++h)                              \
      DST[s][m2][h] = *(const float4_a*)(xbase + (size_t)m2 * 16 * EE +        \
                                         (g) * 128 + s * 32 + h * 4);          \
  }

  LOAD_GROUP(GA, 0);
  STAGE_B(&LB[0][0], 0);
  STAGE_B(&LB[1][0], 1);
  // outstanding: A0=16 (oldest), B0=3, B1=3 -> vmcnt(3) completes A0+B0,
  // keeps B1 in flight.
  asm volatile("s_waitcnt vmcnt(3)" ::: "memory");
  __builtin_amdgcn_s_barrier();
  __builtin_amdgcn_sched_barrier(0);

  int cur = 0;

#define GROUP_BODY(CUR, NXT, g)                                                \
  {                                                                            \
    if ((g) < 7) LOAD_GROUP(NXT, (g) + 1);                                     \
    _Pragma("unroll") for (int s = 0; s < 4; ++s) {                            \
      const int c = 4 * (g) + s;                                               \
      if (c + 2 < 32) {                                                        \
        int sb = cur + 2;                                                      \
        if (sb >= 3) sb -= 3;                                                  \
        STAGE_B(&LB[sb][0], c + 2);                                            \
      }                                                                        \
      short8 af[2];                                                            \
      _Pragma("unroll") for (int m2 = 0; m2 < 2; ++m2)                         \
        af[m2] = pack8(CUR[s][m2][0], CUR[s][m2][1]);                          \
      const unsigned char* Bb = &LB[cur][0];                                   \
      _Pragma("unroll") for (int jj = 0; jj < 6; ++jj) {                       \
        short8 bfv = *(const short8_a*)(Bb + (size_t)(jbase + jj) * 1024 +     \
                                        lane * 16);                            \
        _Pragma("unroll") for (int m2 = 0; m2 < 2; ++m2)                       \
          acc[jj][m2] = mfma_bf16(af[m2], bfv, acc[jj][m2]);                   \
      }                                                                        \
      if (c < 31) {                                                            \
        if (s == 0 && (g) < 7) {                                               \
          /* queue: B(c+1)=3 oldest, A16, B(c+2)=3 -> B(c+1) done */           \
          asm volatile("s_waitcnt vmcnt(19)" ::: "memory");                    \
        } else if (c + 2 < 32) {                                               \
          /* queue: [A16,] B(c+1), B(c+2) -> B(c+1) done */                    \
          asm volatile("s_waitcnt vmcnt(3)" ::: "memory");                     \
        } else {                                                               \
          asm volatile("s_waitcnt vmcnt(0)" ::: "memory");                     \
        }                                                                      \
        __builtin_amdgcn_s_barrier();                                         \
        __builtin_amdgcn_sched_barrier(0);                                     \
      }                                                                        \
      cur = (cur == 2) ? 0 : cur + 1;                                          \
    }                                                                          \
  }

  for (int gp = 0; gp < 4; ++gp) {
    GROUP_BODY(GA, GB, 2 * gp);
    GROUP_BODY(GB, GA, 2 * gp + 1);
  }
#undef GROUP_BODY
#undef LOAD_GROUP
#undef STAGE_B

  const int b = (int)(row0 >> 12);
  const int tt0 = (int)(row0 & (TT - 1));
#pragma unroll
  for (int j = 0; j < 6; ++j) {
    const int jg = jbase + j;
    const int m = jg >> 2;
    const int h0 = (jg & 3) * 16;
#pragma unroll
    for (int m2 = 0; m2 < 2; ++m2) {
      floatx4 a = acc[j][m2];
      const int rbase = mshalf * 32 + m2 * 16 + quad * 4;
      if (m == 0) {
#pragma unroll
        for (int r = 0; r < 4; ++r)
          kws[(row0 + rbase + r) * HH + h0 + l16] = f2bf(a[r]);
      } else if (m == 1) {
        // 0.125 (1/sqrt(H)) * log2(e): attn does p = 2^s
#pragma unroll
        for (int r = 0; r < 4; ++r)
          qws[(row0 + rbase + r) * HH + h0 + l16] = f2bf(a[r] * 0.18033688011112042f);
      } else {  // v transposed [B,64,T]
        uint2 p;
        p.x = pk2(a[0], a[1]);
        p.y = pk2(a[2], a[3]);
        ((uint2_a*)&vtws[(size_t)(b * 64 + h0 + l16) * TT + tt0 + rbase])[0] = p;
      }
    }
  }
}

// ---------------------------------------------------------------------------
// Kernel 3: flash attention. Templated:
//  SPLIT=1: block=(b,jq,split); cid in [0,160) enumerates (jq,s), S(jq)=
//    jq/16+1 splits of key-tile range [0,jq]; 8..17 iters/block, 1280 blocks.
//    Writes partial fp32 (o,l) to slot blockIdx.x; comb_kernel finishes.
//  SPLIT=0 (ws fallback, == verified R5): 512 blocks, paired jq mapping,
//    full key range, in-kernel normalize, direct out write.
// Fixed-reference softmax: p = 2^s (q pre-scaled by 0.125*log2e), masked
// lanes 2^(-1e30) = 0. id = b + 8*cid keeps batch b on XCD b (L2 locality).
// ---------------------------------------------------------------------------
template <bool SPLIT>
__global__ __launch_bounds__(256) void attn_kernel(
    const unsigned short* __restrict__ kws, const unsigned short* __restrict__ qws,
    const unsigned short* __restrict__ vtws, float* __restrict__ dst) {
  __shared__ unsigned short KV[2][16][512];  // 32 KB dbuf
  __shared__ unsigned short pb[4][16][72];   // per-wave P, +8 pad
  const int t = threadIdx.x;
  const int wv = t >> 6, lane = t & 63;
  const int l16 = lane & 15, quad = lane >> 4;
  const int id = (int)blockIdx.x;
  int b, jq, kt0, kt1;
  if (SPLIT) {
    b = id & 7;
    const int cid = id >> 3;  // 0..159
    int s, S;
    if (cid < 16) {
      jq = cid; s = 0; S = 1;
    } else if (cid < 48) {
      const int u = cid - 16; jq = 16 + (u >> 1); s = u & 1; S = 2;
    } else if (cid < 96) {
      const int u = cid - 48; const int d = u / 3; jq = 32 + d; s = u - 3 * d; S = 3;
    } else {
      const int u = cid - 96; jq = 48 + (u >> 2); s = u & 3; S = 4;
    }
    const int n = jq + 1;
    kt0 = (s * n) / S;
    kt1 = ((s + 1) * n) / S;
  } else {
    const int r255 = id & 255;
    b = r255 & 7;
    const int m = r255 >> 3;  // 0..31
    jq = (id < 256) ? m : 63 - m;
    kt0 = 0;
    kt1 = jq + 1;
  }
  const int q0 = jq * 64;
  const int qrow = q0 + wv * 16 + l16;

  const unsigned short* qp = qws + ((size_t)b * TT + qrow) * HH + quad * 8;
  short8 qa0 = *(const short8_a*)(qp);
  short8 qa1 = *(const short8_a*)(qp + 32);

  floatx4 o[4];
#pragma unroll
  for (int nt = 0; nt < 4; ++nt) o[nt] = fzero();
  float lsum = 0.f;

#define STAGE_KV(buf, ks)                                                      \
  {                                                                            \
    _Pragma("unroll") for (int i = 0; i < 4; ++i) {                            \
      const int idx = wv * 4 + i;                                              \
      const unsigned short* gp;                                                \
      if (idx < 8) {                                                           \
        const int nt = idx >> 1, f = idx & 1;                                  \
        gp = kws + ((size_t)b * TT + (ks) + nt * 16 + l16) * HH + f * 32 +     \
             quad * 8;                                                         \
      } else {                                                                 \
        const int nt = (idx - 8) >> 1, f = idx & 1;                            \
        gp = vtws + ((size_t)(b * 64 + nt * 16 + l16)) * TT + (ks) + f * 32 +  \
             quad * 8;                                                         \
      }                                                                        \
      GLDS(gp, &KV[buf][idx][0]);                                              \
    }                                                                          \
  }

  STAGE_KV(0, kt0 * 64);
  __syncthreads();

  for (int kt = kt0; kt < kt1; ++kt) {
    const int cur = (kt - kt0) & 1;
    const int ks = kt * 64;
    if (kt + 1 < kt1) STAGE_KV(cur ^ 1, ks + 64);

    floatx4 sc[4];
#pragma unroll
    for (int nt = 0; nt < 4; ++nt) {
      short8 kf0 = *(const short8_a*)&KV[cur][nt * 2][lane * 8];
      short8 kf1 = *(const short8_a*)&KV[cur][nt * 2 + 1][lane * 8];
      floatx4 z = fzero();
      z = mfma_bf16(kf0, qa0, z);
      z = mfma_bf16(kf1, qa1, z);
      sc[nt] = z;
    }
    if (kt == jq) {  // causal mask on diagonal tile -> exp2 gives exact 0
#pragma unroll
      for (int nt = 0; nt < 4; ++nt)
#pragma unroll
        for (int r = 0; r < 4; ++r) {
          const int key = ks + nt * 16 + quad * 4 + r;
          if (key > qrow) sc[nt][r] = -1e30f;
        }
    }
    // fixed-reference softmax: p = 2^s (s already in log2 domain)
#pragma unroll
    for (int nt = 0; nt < 4; ++nt) {
      const float p0 = exp2f(sc[nt][0]);
      const float p1 = exp2f(sc[nt][1]);
      const float p2 = exp2f(sc[nt][2]);
      const float p3 = exp2f(sc[nt][3]);
      lsum += (p0 + p1) + (p2 + p3);
      uint2 pw;
      pw.x = pk2(p0, p1);
      pw.y = pk2(p2, p3);
      ((uint2_a*)&pb[wv][l16][nt * 16 + quad * 4])[0] = pw;
    }
    // P frags (same-wave LDS RAW; lgkmcnt handles)
    short8 pf0 = *(const short8_a*)&pb[wv][l16][quad * 8];
    short8 pf1 = *(const short8_a*)&pb[wv][l16][quad * 8 + 32];
#pragma unroll
    for (int nt = 0; nt < 4; ++nt) {
      short8 vf0 = *(const short8_a*)&KV[cur][8 + nt * 2][lane * 8];
      short8 vf1 = *(const short8_a*)&KV[cur][8 + nt * 2 + 1][lane * 8];
      o[nt] = mfma_bf16(vf0, pf0, o[nt]);
      o[nt] = mfma_bf16(vf1, pf1, o[nt]);
    }
    __syncthreads();
  }
#undef STAGE_KV

  // l over the 4 quads of this query column
  float lr = lsum;
  lr += __shfl_xor(lr, 16);
  lr += __shfl_xor(lr, 32);

  if (SPLIT) {
    float* op = dst + (size_t)id * SLOTF;
    const int ql = wv * 16 + l16;
#pragma unroll
    for (int nt = 0; nt < 4; ++nt) {
      float4 st;
      st.x = o[nt][0];
      st.y = o[nt][1];
      st.z = o[nt][2];
      st.w = o[nt][3];
      *(float4_a*)&op[(size_t)ql * 64 + nt * 16 + quad * 4] = st;
    }
    if (lane < 16) op[4096 + wv * 16 + lane] = lr;
  } else {
    const float inv = 1.0f / lr;
#pragma unroll
    for (int nt = 0; nt < 4; ++nt) {
      float4 st;
      st.x = o[nt][0] * inv;
      st.y = o[nt][1] * inv;
      st.z = o[nt][2] * inv;
      st.w = o[nt][3] * inv;
      *(float4_a*)&dst[((size_t)b * TT + qrow) * HH + nt * 16 + quad * 4] = st;
    }
  }
}

// ---------------------------------------------------------------------------
// Kernel 4 (split path): combine partials. 512 blocks = (b, jq); sums S(jq)
// slots of (o, l), writes out = o_sum / l_sum. Slots written by same-b attn
// blocks live on the same XCD (id = b mod 8) -> mostly L2 reads.
// ---------------------------------------------------------------------------
__global__ __launch_bounds__(256) void comb_kernel(
    const float* __restrict__ part, float* __restrict__ out) {
  const int id = (int)blockIdx.x;
  const int b = id & 7;
  const int jq = id >> 3;  // 0..63
  const int tq = jq >> 4;
  const int S = tq + 1;
  const int P = 8 * tq * (tq + 1) + (jq & 15) * S;  // prefix of (jq,0) in cid space
  const int t = threadIdx.x;
  const int r0 = t >> 6;   // 0..3
  const int h = t & 63;
  const float* s0 = part + (size_t)(b + 8 * P) * SLOTF;
  const size_t sstr = (size_t)8 * SLOTF;  // slot stride between consecutive s

#pragma unroll 4
  for (int i = 0; i < 16; ++i) {
    const int r = i * 4 + r0;
    float acc = 0.f, l = 0.f;
    for (int s2 = 0; s2 < S; ++s2) {
      acc += s0[(size_t)s2 * sstr + (size_t)r * 64 + h];
      l += s0[(size_t)s2 * sstr + 4096 + r];
    }
    out[((size_t)b * TT + jq * 64 + r) * HH + h] = acc / l;
  }
}

// ---------------------------------------------------------------------------
extern "C" void kernel_launch(void* const* d_in, const int* in_sizes, int n_in,
                              void* d_out, int out_size, void* d_ws, size_t ws_size,
                              hipStream_t stream) {
  const float* x = (const float*)d_in[0];
  const float* Wk = (const float*)d_in[1];
  const float* Wq = (const float*)d_in[2];
  const float* Wv = (const float*)d_in[3];
  float* out = (float*)d_out;

  // ws layout: k bf16 [B,T,64] | q bf16 [B,T,64] | vT bf16 [B,64,T] |
  //            wt3 bf16 [3,64,1024] | partials fp32 [1280][4160] (if room)
  unsigned short* kws = (unsigned short*)d_ws;
  unsigned short* qws = kws + (size_t)BB * TT * HH;
  unsigned short* vtws = qws + (size_t)BB * TT * HH;
  unsigned short* wt3 = vtws + (size_t)BB * TT * HH;
  float* part = (float*)(wt3 + (size_t)3 * HH * EE);

  const size_t base_bytes = (size_t)3 * BB * TT * HH * 2 + (size_t)3 * HH * EE * 2;
  const size_t need = base_bytes + (size_t)BB * NSLOT * SLOTF * 4;
  const bool use_split = (ws_size >= need);

  hipLaunchKernelGGL(wt_kernel, dim3(16, 3), dim3(256), 0, stream, Wk, Wq, Wv, wt3);
  hipLaunchKernelGGL(proj_kernel, dim3(512), dim3(256), 0, stream, x, wt3, kws, qws,
                     vtws);
  if (use_split) {
    hipLaunchKernelGGL((attn_kernel<true>), dim3(BB * NSLOT), dim3(256), 0, stream,
                       kws, qws, vtws, part);
    hipLaunchKernelGGL(comb_kernel, dim3(512), dim3(256), 0, stream, part, out);
  } else {
    hipLaunchKernelGGL((attn_kernel<false>), dim3(512), dim3(256), 0, stream,
                       kws, qws, vtws, out);
  }
}